// Round 2
// baseline (591.149 us; speedup 1.0000x reference)
//
#include <hip/hip_runtime.h>
#include <hip/hip_bf16.h>
#include <cstdint>

// Problem constants
#define NB    524288      // batch rows
#define NDIN  32
#define NH    128
#define NLD   16
#define NNE   512

// d_out element offsets (float32 elements)
#define OFF_ZQ   0
#define OFF_SC   8388608
#define OFF_RS   8912896
#define OFF_LOSS 9437184
#define OFF_IDS  9437185

// d_ws float layout
#define WS_LOSS 0
#define WS_W1D  64
#define WS_W1S  (64 + 4096)
#define WS_W1R  (64 + 8192)
#define WS_CBT  (64 + 12288)
#define WS_C2   (64 + 12288 + 8192)

// ---------------------------------------------------------------------------
// Prep: transpose W1 matrices (32x128 -> 128x32), codebook (16x512 -> 512x16),
// precompute ||c_j||^2 with numpy's pairwise (8-accumulator) order over n=16,
// zero loss accumulator.
// ---------------------------------------------------------------------------
__global__ __launch_bounds__(256) void prep_kernel(
    const float* __restrict__ cb,
    const float* __restrict__ w1d, const float* __restrict__ w1s,
    const float* __restrict__ w1r, float* __restrict__ ws)
{
    int gid = blockIdx.x * 256 + threadIdx.x;
    if (gid == 0) ws[WS_LOSS] = 0.0f;
    if (gid < 4096) {
        int j = gid >> 5, k = gid & 31;           // dest [j][k] <- src [k][j]
        ws[WS_W1D + gid] = w1d[k * NH + j];
        ws[WS_W1S + gid] = w1s[k * NH + j];
        ws[WS_W1R + gid] = w1r[k * NH + j];
    } else if (gid < 4096 + 8192) {
        int idx = gid - 4096;
        int j = idx >> 4, k = idx & 15;           // cbT[j][k] = cb[k][j]
        ws[WS_CBT + idx] = cb[k * NNE + j];
    } else if (gid < 4096 + 8192 + 512) {
        int j = gid - (4096 + 8192);
        // numpy: tmp = cb*cb (each rounded), then add.reduce axis 0 pairwise:
        // r[m] = t[m] + t[m+8]; ((r0+r1)+(r2+r3)) + ((r4+r5)+(r6+r7))
        float t[16];
#pragma unroll
        for (int k = 0; k < 16; ++k) {
            float c = cb[k * NNE + j];
            t[k] = __fmul_rn(c, c);
        }
        float r8[8];
#pragma unroll
        for (int m = 0; m < 8; ++m) r8[m] = __fadd_rn(t[m], t[m + 8]);
        float acc = __fadd_rn(
            __fadd_rn(__fadd_rn(r8[0], r8[1]), __fadd_rn(r8[2], r8[3])),
            __fadd_rn(__fadd_rn(r8[4], r8[5]), __fadd_rn(r8[6], r8[7])));
        ws[WS_C2 + j] = acc;
    }
}

// ---------------------------------------------------------------------------
// Main: one thread per row. All weight/codebook indices are wave-uniform ->
// scalar loads. fp32 with numpy-matching op order for the argmin path.
// ---------------------------------------------------------------------------
__global__ __launch_bounds__(256) void main_kernel(
    const float* __restrict__ z,
    const float* __restrict__ b1d, const float* __restrict__ w2d, const float* __restrict__ b2d,
    const float* __restrict__ b1s, const float* __restrict__ w2s, const float* __restrict__ b2s,
    const float* __restrict__ b1r, const float* __restrict__ w2r, const float* __restrict__ b2r,
    const float* __restrict__ ws,
    float* __restrict__ loss_acc,
    float* __restrict__ out)
{
    const int i = blockIdx.x * 256 + threadIdx.x;

    const float* __restrict__ w1dT = ws + WS_W1D;
    const float* __restrict__ w1sT = ws + WS_W1S;
    const float* __restrict__ w1rT = ws + WS_W1R;
    const float* __restrict__ cbT  = ws + WS_CBT;
    const float* __restrict__ c2   = ws + WS_C2;

    // load row (32 floats, 8x float4)
    float x[32];
    const float4* zv = reinterpret_cast<const float4*>(z) + (size_t)i * 8;
#pragma unroll
    for (int m = 0; m < 8; ++m) {
        float4 v = zv[m];
        x[4*m+0] = v.x; x[4*m+1] = v.y; x[4*m+2] = v.z; x[4*m+3] = v.w;
    }

    float zd[16];
#pragma unroll
    for (int l = 0; l < 16; ++l) zd[l] = 0.0f;
    float sacc = 0.0f, racc = 0.0f;

    // fused first+second layers of the three MLPs, hidden unit j at a time.
    // Sequential-k FMA matches BLAS sgemm/sgemv K-loop order.
#pragma unroll 2
    for (int j = 0; j < NH; ++j) {
        float hd = 0.0f, hs = 0.0f, hr = 0.0f;
        const float* wd = w1dT + j * 32;
        const float* wsrow = w1sT + j * 32;
        const float* wr = w1rT + j * 32;
#pragma unroll
        for (int k = 0; k < 32; ++k) {
            hd = __fmaf_rn(x[k], wd[k], hd);
            hs = __fmaf_rn(x[k], wsrow[k], hs);
            hr = __fmaf_rn(x[k], wr[k], hr);
        }
        hd = fmaxf(__fadd_rn(hd, b1d[j]), 0.0f);
        hs = fmaxf(__fadd_rn(hs, b1s[j]), 0.0f);
        hr = fmaxf(__fadd_rn(hr, b1r[j]), 0.0f);
        const float* w2row = w2d + j * 16;
#pragma unroll
        for (int l = 0; l < 16; ++l) zd[l] = __fmaf_rn(hd, w2row[l], zd[l]);
        sacc = __fmaf_rn(hs, w2s[j], sacc);
        racc = __fmaf_rn(hr, w2r[j], racc);
    }
#pragma unroll
    for (int l = 0; l < 16; ++l) zd[l] = __fadd_rn(zd[l], b2d[l]);

    float scaler   = __fadd_rn(sacc, b2s[0]);
    float redshift = fmaxf(__fadd_rn(racc, b2r[0]), 0.0f);

    // s = np.sum(zf*zf, axis=1): numpy pairwise, 8 accumulators + tree
    float sq[16];
#pragma unroll
    for (int l = 0; l < 16; ++l) sq[l] = __fmul_rn(zd[l], zd[l]);
    float rr[8];
#pragma unroll
    for (int m = 0; m < 8; ++m) rr[m] = __fadd_rn(sq[m], sq[m + 8]);
    float s = __fadd_rn(
        __fadd_rn(__fadd_rn(rr[0], rr[1]), __fadd_rn(rr[2], rr[3])),
        __fadd_rn(__fadd_rn(rr[4], rr[5]), __fadd_rn(rr[6], rr[7])));

    // VQ argmin: d_j = (s - 2*(zf.c_j)) + ||c_j||^2, first-index tie-break
    float best = 3.4028235e38f;
    int bid = 0;
#pragma unroll 4
    for (int j = 0; j < NNE; ++j) {
        const float* cj = cbT + j * 16;
        float b = __fmul_rn(zd[0], cj[0]);
#pragma unroll
        for (int k = 1; k < 16; ++k) b = __fmaf_rn(zd[k], cj[k], b);
        float dj = __fadd_rn(__fsub_rn(s, __fmul_rn(2.0f, b)), c2[j]);
        if (dj < best) { best = dj; bid = j; }
    }

    // gather z_q, z_q_st = zd + (z_q - zd) in f32, loss partial
    float lsum = 0.0f;
    float o[16];
#pragma unroll
    for (int l = 0; l < 16; ++l) {
        float q = cbT[bid * 16 + l];
        float d = __fsub_rn(q, zd[l]);
        lsum = __fmaf_rn(d, d, lsum);
        o[l] = __fadd_rn(zd[l], d);
    }
    float4* ozq = reinterpret_cast<float4*>(out) + (size_t)i * 4;
    ozq[0] = make_float4(o[0],  o[1],  o[2],  o[3]);
    ozq[1] = make_float4(o[4],  o[5],  o[6],  o[7]);
    ozq[2] = make_float4(o[8],  o[9],  o[10], o[11]);
    ozq[3] = make_float4(o[12], o[13], o[14], o[15]);

    out[OFF_SC  + i] = scaler;
    out[OFF_RS  + i] = redshift;
    out[OFF_IDS + i] = (float)bid;

    // loss reduction: wave shuffle -> LDS -> one atomic per block
#pragma unroll
    for (int off = 32; off > 0; off >>= 1) lsum += __shfl_down(lsum, off);
    __shared__ float red[4];
    if ((threadIdx.x & 63) == 0) red[threadIdx.x >> 6] = lsum;
    __syncthreads();
    if (threadIdx.x == 0)
        atomicAdd(loss_acc, red[0] + red[1] + red[2] + red[3]);
}

__global__ void fin_kernel(const float* __restrict__ ws, float* __restrict__ out) {
    float m = ws[WS_LOSS] / 8388608.0f;   // mean over B*LD
    out[OFF_LOSS] = m + 0.25f * m;        // (1 + BETA) * mean
}

extern "C" void kernel_launch(void* const* d_in, const int* in_sizes, int n_in,
                              void* d_out, int out_size, void* d_ws, size_t ws_size,
                              hipStream_t stream)
{
    const float* z      = (const float*)d_in[0];
    const float* cb     = (const float*)d_in[1];
    const float* dec_w1 = (const float*)d_in[2];
    const float* dec_b1 = (const float*)d_in[3];
    const float* dec_w2 = (const float*)d_in[4];
    const float* dec_b2 = (const float*)d_in[5];
    const float* sc_w1  = (const float*)d_in[6];
    const float* sc_b1  = (const float*)d_in[7];
    const float* sc_w2  = (const float*)d_in[8];
    const float* sc_b2  = (const float*)d_in[9];
    const float* rs_w1  = (const float*)d_in[10];
    const float* rs_b1  = (const float*)d_in[11];
    const float* rs_w2  = (const float*)d_in[12];
    const float* rs_b2  = (const float*)d_in[13];

    float* ws = (float*)d_ws;
    float* out = (float*)d_out;

    prep_kernel<<<50, 256, 0, stream>>>(cb, dec_w1, sc_w1, rs_w1, ws);
    main_kernel<<<NB / 256, 256, 0, stream>>>(
        z,
        dec_b1, dec_w2, dec_b2,
        sc_b1,  sc_w2,  sc_b2,
        rs_b1,  rs_w2,  rs_b2,
        ws, ws + WS_LOSS, out);
    fin_kernel<<<1, 1, 0, stream>>>(ws, out);
}